// Round 7
// baseline (256.513 us; speedup 1.0000x reference)
//
#include <hip/hip_runtime.h>

// Problem constants: B=2, S=2048, D=1024, H=16, HD=64
#define SS 2048
#define SD 1024
#define SH 16
#define SHD 64
#define MROWS 4096
#define LOG2E 1.44269504088896340736f

typedef __attribute__((ext_vector_type(8))) short short8;
typedef __attribute__((ext_vector_type(4))) short short4v;
typedef __attribute__((ext_vector_type(4))) float floatx4;
typedef __attribute__((ext_vector_type(4))) unsigned short ushort4v;
typedef unsigned short u16;
typedef unsigned int u32;

#define AS1 __attribute__((address_space(1)))
#define AS3 __attribute__((address_space(3)))

__device__ inline u16 f2bf(float v) {
  u32 x = __builtin_bit_cast(u32, v);
  x = x + 0x7fffu + ((x >> 16) & 1u);   // RNE; inputs finite
  return (u16)(x >> 16);
}

// ---------------- fused cast kernel (all fp32 -> bf16 inputs) -------------
__global__ __launch_bounds__(256) void cast_all(
    const float* __restrict__ q, const float* __restrict__ k,
    const float* __restrict__ v, const float* __restrict__ wq,
    const float* __restrict__ wk, const float* __restrict__ wv,
    const float* __restrict__ wo, u16* __restrict__ out) {
  int i = blockIdx.x * 256 + threadIdx.x;
  const float* src;
  int idx;
  if (i < 3145728) {
    int a = i >> 20;
    src = (a == 0) ? q : ((a == 1) ? k : v);
    idx = i & 1048575;
  } else {
    int j = i - 3145728;
    int a = j >> 18;
    src = (a == 0) ? wq : ((a == 1) ? wk : ((a == 2) ? wv : wo));
    idx = j & 262143;
  }
  float4 f = ((const float4*)src)[idx];
  ushort4v o;
  o[0] = f2bf(f.x); o[1] = f2bf(f.y); o[2] = f2bf(f.z); o[3] = f2bf(f.w);
  ((ushort4v*)out)[i] = o;
}

// ---------------- GEMM: C[M,N] = A[M,K] @ W[N,K]^T + bias ----------------
// mode 0: bf16 out; z=0 -> q [B,H,S,HD] (scaled), z=1 -> k [B,H,S,HD],
//         z=2 -> V in PV-fragment-major layout (see attn).
// mode 1: fp32 out row-major.
// z<2 / mode 1 use SWAPPED mfma operands (C^T orientation): lane then holds
// 4 consecutive N-indices -> coalesced b64/b128 stores (16 store instrs vs 64
// scalar stores in C-orientation).
__global__ __launch_bounds__(256) void gemm_bt(
    const u16* __restrict__ Aall, const u16* __restrict__ Wall,
    const float* __restrict__ b0, const float* __restrict__ b1,
    const float* __restrict__ b2, u16* __restrict__ outb,
    float* __restrict__ outf, int mode, float qscale) {
  __shared__ u16 lds_a[128 * 32];
  __shared__ u16 lds_w[128 * 32];
  int z = blockIdx.z;
  const u16* A = Aall + (size_t)z * (MROWS * (size_t)SD);
  const u16* W = Wall + (size_t)z * (SD * (size_t)SD);
  const float* bias = (z == 0) ? b0 : ((z == 1) ? b1 : b2);
  float scale = (mode == 0 && z == 0) ? qscale : 1.0f;

  int tid = threadIdx.x;
  int lane = tid & 63, wave = tid >> 6;
  int l16 = lane & 15, quad = lane >> 4;
  int wm = (wave >> 1) * 64, wn = (wave & 1) * 64;
  int tm = blockIdx.y * 128, tn = blockIdx.x * 128;

  floatx4 acc[4][4];
  floatx4 zf = {0.f, 0.f, 0.f, 0.f};
#pragma unroll
  for (int r = 0; r < 4; r++)
#pragma unroll
    for (int c = 0; c < 4; c++) acc[r][c] = zf;

  int srow = wave * 16 + (lane >> 2);
  int scol8 = (lane & 3) * 8;
  const u16* pa0 = A + (size_t)(tm + srow) * SD + scol8;
  const u16* pa1 = pa0 + (size_t)64 * SD;
  const u16* pw0 = W + (size_t)(tn + srow) * SD + scol8;
  const u16* pw1 = pw0 + (size_t)64 * SD;
  AS3 u16* la0 = (AS3 u16*)&lds_a[wave * 512];
  AS3 u16* la1 = (AS3 u16*)&lds_a[(wave + 4) * 512];
  AS3 u16* lw0 = (AS3 u16*)&lds_w[wave * 512];
  AS3 u16* lw1 = (AS3 u16*)&lds_w[(wave + 4) * 512];

  bool vlayout = (mode == 0 && z == 2);

  if (!vlayout) {
    // ---- swapped orientation: D[gn on quad*4+g][gm on l16] ----
    for (int k0 = 0; k0 < SD; k0 += 32) {
      __builtin_amdgcn_global_load_lds((const AS1 void*)pa0, (AS3 void*)la0, 16, 0, 0);
      __builtin_amdgcn_global_load_lds((const AS1 void*)pa1, (AS3 void*)la1, 16, 0, 0);
      __builtin_amdgcn_global_load_lds((const AS1 void*)pw0, (AS3 void*)lw0, 16, 0, 0);
      __builtin_amdgcn_global_load_lds((const AS1 void*)pw1, (AS3 void*)lw1, 16, 0, 0);
      pa0 += 32; pa1 += 32; pw0 += 32; pw1 += 32;
      __syncthreads();
      short8 af[4], wf[4];
#pragma unroll
      for (int r = 0; r < 4; r++)
        af[r] = *(short8*)&lds_a[(wm + r * 16 + l16) * 32 + quad * 8];
#pragma unroll
      for (int c = 0; c < 4; c++)
        wf[c] = *(short8*)&lds_w[(wn + c * 16 + l16) * 32 + quad * 8];
#pragma unroll
      for (int r = 0; r < 4; r++)
#pragma unroll
        for (int c = 0; c < 4; c++)
          acc[r][c] = __builtin_amdgcn_mfma_f32_16x16x32_bf16(wf[c], af[r], acc[r][c], 0, 0, 0);
      __syncthreads();
    }

    if (mode == 0) {
      // q/k -> [B,H,S,HD], b64 packed stores (4 consecutive hd per lane)
      u16* ob = outb + (size_t)z * (MROWS * (size_t)SD);
      int h = (tn + wn) >> 6;
#pragma unroll
      for (int c = 0; c < 4; c++) {
        float4 bv = *(const float4*)&bias[tn + wn + c * 16 + quad * 4];
#pragma unroll
        for (int r = 0; r < 4; r++) {
          int ss = tm + wm + r * 16 + l16;
          int bb = ss >> 11, ssl = ss & 2047;
          ushort4v pk;
          pk[0] = f2bf((acc[r][c][0] + bv.x) * scale);
          pk[1] = f2bf((acc[r][c][1] + bv.y) * scale);
          pk[2] = f2bf((acc[r][c][2] + bv.z) * scale);
          pk[3] = f2bf((acc[r][c][3] + bv.w) * scale);
          *(ushort4v*)&ob[(size_t)(((bb * SH + h) * SS + ssl) * SHD) + c * 16 + quad * 4] = pk;
        }
      }
    } else {
      // fp32 row-major, b128 stores (4 consecutive gn per lane)
#pragma unroll
      for (int c = 0; c < 4; c++) {
        float4 bv = *(const float4*)&bias[tn + wn + c * 16 + quad * 4];
#pragma unroll
        for (int r = 0; r < 4; r++) {
          int gm = tm + wm + r * 16 + l16;
          float4 o;
          o.x = acc[r][c][0] + bv.x;
          o.y = acc[r][c][1] + bv.y;
          o.z = acc[r][c][2] + bv.z;
          o.w = acc[r][c][3] + bv.w;
          *(float4*)&outf[(size_t)gm * SD + tn + wn + c * 16 + quad * 4] = o;
        }
      }
    }
  } else {
    // ---- original orientation (V fragment-major epilogue needs key on quad) ----
    for (int k0 = 0; k0 < SD; k0 += 32) {
      __builtin_amdgcn_global_load_lds((const AS1 void*)pa0, (AS3 void*)la0, 16, 0, 0);
      __builtin_amdgcn_global_load_lds((const AS1 void*)pa1, (AS3 void*)la1, 16, 0, 0);
      __builtin_amdgcn_global_load_lds((const AS1 void*)pw0, (AS3 void*)lw0, 16, 0, 0);
      __builtin_amdgcn_global_load_lds((const AS1 void*)pw1, (AS3 void*)lw1, 16, 0, 0);
      pa0 += 32; pa1 += 32; pw0 += 32; pw1 += 32;
      __syncthreads();
      short8 af[4], wf[4];
#pragma unroll
      for (int r = 0; r < 4; r++)
        af[r] = *(short8*)&lds_a[(wm + r * 16 + l16) * 32 + quad * 8];
#pragma unroll
      for (int c = 0; c < 4; c++)
        wf[c] = *(short8*)&lds_w[(wn + c * 16 + l16) * 32 + quad * 8];
#pragma unroll
      for (int r = 0; r < 4; r++)
#pragma unroll
        for (int c = 0; c < 4; c++)
          acc[r][c] = __builtin_amdgcn_mfma_f32_16x16x32_bf16(af[r], wf[c], acc[r][c], 0, 0, 0);
      __syncthreads();
    }

    // V in PV-fragment-major layout. Per head, per 64-key tile kt: 8 blocks
    // (c*2+ct2) of 512 elems; lane slot (l16*4+quad)*8; elems [half*4+j] =
    // V[key=kt*64+ct*16+quad*4+j, hd=c*16+l16], ct=2*ct2+half.
    u16* ob = outb + (size_t)z * (MROWS * (size_t)SD);
    int h = (tn + wn) >> 6;
    int bb = (tm + wm) >> 11;
    int kt = ((tm + wm) & 2047) >> 6;
    u16* vbase = ob + (size_t)(bb * SH + h) * (SS * SHD) + (size_t)kt * 4096 +
                 (l16 * 4 + quad) * 8;
#pragma unroll
    for (int c = 0; c < 4; c++) {
      int gn = tn + wn + c * 16 + l16;
      float bv = bias[gn];
#pragma unroll
      for (int rp = 0; rp < 2; rp++) {
        union { u16 u[8]; short8 s; } pk;
#pragma unroll
        for (int g = 0; g < 4; g++) {
          pk.u[g]     = f2bf(acc[2 * rp][c][g] + bv);
          pk.u[4 + g] = f2bf(acc[2 * rp + 1][c][g] + bv);
        }
        *(short8*)&vbase[(c * 2 + rp) * 512] = pk.s;
      }
    }
  }
}

// ---------------- flash attention v6 ----------------
// 64 q-rows per single-wave block; zero LDS, zero barriers. S^T trick:
// QK^T as mfma(A=K, B=Q) -> C holds q on l16, key on quad*4+r = A-fragment
// layout of mfma_f32_16x16x16bf16_1k -> P feeds PV with no transform.
// K: direct-global b128 fragment loads; V: direct-global b64 loads that land
// MFMA-operand-ready (no sub-register extraction VALU). Register
// double-buffered (1-iter prefetch distance). Row sums via ones-column MFMA.
__global__ __launch_bounds__(64, 1) void attn(
    const u16* __restrict__ qb, const u16* __restrict__ kb,
    const u16* __restrict__ vfrag, u16* __restrict__ ctxb) {
  int lane = threadIdx.x & 63;
  int l16 = lane & 15, quad = lane >> 4;

  // XCD swizzle: 4 heads per XCD residue (2 MB K+V working set per L2)
  int raw = blockIdx.x;                // 0..1023
  int xcd = raw & 7, slot = raw >> 3;  // slot 0..127
  int bh = xcd + 8 * (slot >> 5);
  int qt = slot & 31;
  int b = bh >> 4, h = bh & 15;
  int base = bh * (SS * SHD);
  int q0 = qt * 64;

  const u16* kp = kb + base + l16 * 64 + quad * 8;        // + kt*4096 + ct*1024 + hh*32
  const u16* vp = vfrag + base + (l16 * 4 + quad) * 8;    // + kt*4096 + blk*512 (+half*4)

  // Q fragments (B operand of S^T): n=q=l16, k=hd=quad*8+j
  short8 qf[4][2];
#pragma unroll
  for (int t = 0; t < 4; t++)
#pragma unroll
    for (int hh = 0; hh < 2; hh++)
      qf[t][hh] = *(const short8*)&qb[base + (q0 + t * 16 + l16) * SHD + hh * 32 + quad * 8];

  floatx4 zf = {0.f, 0.f, 0.f, 0.f};
  floatx4 acc[4][4], accl[4];
#pragma unroll
  for (int t = 0; t < 4; t++) {
    accl[t] = zf;
#pragma unroll
    for (int c = 0; c < 4; c++) acc[t][c] = zf;
  }
  const short4v ones = {0x3F80, 0x3F80, 0x3F80, 0x3F80};  // bf16 1.0 x4

  auto loadK = [&](short8 (&dst)[4][2], int kt) {
    const u16* p = kp + kt * 4096;
#pragma unroll
    for (int ct = 0; ct < 4; ct++)
#pragma unroll
      for (int hh = 0; hh < 2; hh++)
        dst[ct][hh] = *(const short8*)&p[ct * 1024 + hh * 32];
  };
  auto loadV = [&](short4v (&dst)[4][4], int kt) {
    const u16* p = vp + kt * 4096;
#pragma unroll
    for (int c = 0; c < 4; c++)
#pragma unroll
      for (int ct = 0; ct < 4; ct++)
        dst[c][ct] = *(const short4v*)&p[(c * 2 + (ct >> 1)) * 512 + (ct & 1) * 4];
  };
  auto compute = [&](short8 (&kf)[4][2], short4v (&vf)[4][4]) {
#pragma unroll
    for (int ct = 0; ct < 4; ct++) {
      floatx4 sc[4];
#pragma unroll
      for (int t = 0; t < 4; t++) {
        floatx4 zz = zf;
        zz = __builtin_amdgcn_mfma_f32_16x16x32_bf16(kf[ct][0], qf[t][0], zz, 0, 0, 0);
        zz = __builtin_amdgcn_mfma_f32_16x16x32_bf16(kf[ct][1], qf[t][1], zz, 0, 0, 0);
        sc[t] = zz;
      }
#pragma unroll
      for (int t = 0; t < 4; t++) {
        u32 p0 = __builtin_bit_cast(u32, __builtin_amdgcn_exp2f(sc[t][0]));
        u32 p1 = __builtin_bit_cast(u32, __builtin_amdgcn_exp2f(sc[t][1]));
        u32 p2 = __builtin_bit_cast(u32, __builtin_amdgcn_exp2f(sc[t][2]));
        u32 p3 = __builtin_bit_cast(u32, __builtin_amdgcn_exp2f(sc[t][3]));
        union { u32 u[2]; short4v s; } cv;
        cv.u[0] = __builtin_amdgcn_perm(p1, p0, 0x07060302);  // p1.hi16|p0.hi16
        cv.u[1] = __builtin_amdgcn_perm(p3, p2, 0x07060302);
#pragma unroll
        for (int c = 0; c < 4; c++)
          acc[t][c] = __builtin_amdgcn_mfma_f32_16x16x16bf16_1k(cv.s, vf[c][ct], acc[t][c], 0, 0, 0);
        accl[t] = __builtin_amdgcn_mfma_f32_16x16x16bf16_1k(cv.s, ones, accl[t], 0, 0, 0);
      }
    }
  };

  short8 kfa[4][2], kfb[4][2];
  short4v vfa[4][4], vfb[4][4];
  loadK(kfa, 0);
  loadV(vfa, 0);
#pragma unroll 1
  for (int kt2 = 0; kt2 < 16; kt2++) {
    int kt = kt2 * 2;
    loadK(kfb, kt + 1);
    loadV(vfb, kt + 1);
    compute(kfa, vfa);
    int ktn = (kt + 2) & 31;   // wrap-safe dummy prefetch on last iter
    loadK(kfa, ktn);
    loadV(vfa, ktn);
    compute(kfb, vfb);
  }

  // epilogue: l per-row in accl (no shuffles)
#pragma unroll
  for (int t = 0; t < 4; t++) {
#pragma unroll
    for (int g = 0; g < 4; g++) {
      float invg = 1.0f / accl[t][g];
      int qrow = q0 + t * 16 + quad * 4 + g;
#pragma unroll
      for (int c = 0; c < 4; c++) {
        int hd = c * 16 + l16;
        ctxb[(size_t)((b * SS + qrow) * SD + h * SHD + hd)] = f2bf(acc[t][c][g] * invg);
      }
    }
  }
}

// ---------------- launch ----------------
extern "C" void kernel_launch(void* const* d_in, const int* in_sizes, int n_in,
                              void* d_out, int out_size, void* d_ws, size_t ws_size,
                              hipStream_t stream) {
  const float* Q  = (const float*)d_in[0];
  const float* Kp = (const float*)d_in[1];
  const float* Vp = (const float*)d_in[2];
  const float* Wq = (const float*)d_in[3];
  const float* bq = (const float*)d_in[4];
  const float* Wk = (const float*)d_in[5];
  const float* bk = (const float*)d_in[6];
  const float* Wv = (const float*)d_in[7];
  const float* bv = (const float*)d_in[8];
  const float* Wo = (const float*)d_in[9];
  const float* bo = (const float*)d_in[10];

  u16* xb   = (u16*)d_ws;                        // 3 * 4,194,304  bf16 Q,K,V
  u16* wb   = xb + (size_t)3 * 4194304;          // 4 * 1,048,576  bf16 weights
  u16* qkvb = wb + (size_t)4 * 1048576;          // q,k [B,H,S,HD]; V fragment-major
  u16* ctxb = qkvb + (size_t)3 * 4194304;        // ctx [B,S,D]
  float* out = (float*)d_out;

  cast_all<<<dim3(16384), dim3(256), 0, stream>>>(Q, Kp, Vp, Wq, Wk, Wv, Wo, xb);

  const float qscale = 0.125f * LOG2E;
  gemm_bt<<<dim3(8, 32, 3), dim3(256), 0, stream>>>(
      xb, wb, bq, bk, bv, qkvb, (float*)nullptr, 0, qscale);

  attn<<<dim3(1024), dim3(64), 0, stream>>>(
      qkvb, qkvb + (size_t)4194304, qkvb + (size_t)2 * 4194304, ctxb);

  gemm_bt<<<dim3(8, 32, 1), dim3(256), 0, stream>>>(
      ctxb, wb + (size_t)3 * 1048576, bo, bo, bo,
      (u16*)nullptr, out, 1, 1.0f);
}